// Round 9
// baseline (1332.325 us; speedup 1.0000x reference)
//
#include <hip/hip_runtime.h>

#define NN 50000
#define HH 202
#define EE 100000
#define PMX 1024
#define NKT 7          // k-steps of 32 (K padded to 224; B packs zero-padded)
#define PKSZ (13 * NKT * 64 * 8)   // ushorts per B pack = 46592
#define NEDG (6 * EE)
#define AFR (4 * NKT * 64 * 8)     // ushorts per fragment-order A tile = 14336

typedef __attribute__((ext_vector_type(8))) short short8;
typedef __attribute__((ext_vector_type(4))) float v4f;

__device__ __forceinline__ float sigf(float x) { return 1.0f / (1.0f + expf(-x)); }

__device__ __forceinline__ unsigned short f2bf(float x) {
    unsigned int u = __float_as_uint(x);
    unsigned int r = (u + 0x7fffu + ((u >> 16) & 1u)) >> 16;
    return (unsigned short)r;
}
__device__ __forceinline__ float bf2f(unsigned short u) {
    return __uint_as_float(((unsigned int)u) << 16);
}

// fragment-order LDS offset for element (row in [0,64), k in [0,224)), k even pair base:
// slice rf=row>>4 holds wave rf's A; lane = (k>>3&3)*16 + (row&15); j = k&7
__device__ __forceinline__ int frag_off(int row, int k) {
    return (((row >> 4) * NKT + (k >> 5)) * 64 + ((k >> 3) & 3) * 16 + (row & 15)) * 8 + (k & 7);
}

// gate[p][j] = bf16( 2*sigmoid(sum_k pt[p][k]*pos_W[k][j] + pos_b[j]) )
__global__ void gate_kernel(const float* __restrict__ pos_W, const float* __restrict__ pos_b,
                            unsigned short* __restrict__ gate) {
    int p = blockIdx.x;
    __shared__ float pt[HH];
    int t = threadIdx.x;
    if (t < HH) {
        float v;
        if (t < 101) {
            float invf = expf(-(2.0f * t / 202.0f) * 9.210340371976184f); // ln(10000)
            v = sinf((float)p * invf);
        } else {
            int k = t - 101;
            float invf = expf(-(2.0f * k / 202.0f) * 9.210340371976184f);
            v = cosf((float)p * invf);
        }
        pt[t] = v;
    }
    __syncthreads();
    for (int j = t; j < HH; j += blockDim.x) {
        float acc = pos_b[j];
        for (int k = 0; k < HH; ++k) acc += pt[k] * pos_W[k * HH + j];
        gate[p * HH + j] = f2bf(2.0f * sigf(acc));
    }
}

// Pack B into MFMA fragment order, f32 -> bf16 (zeros for k or j >= 202).
// BP[((cf*NKT + kt)*64 + l)*8 + jj] = B[k][j], k = kt*32 + (l>>4)*8 + jj, j = cf*16 + (l&15)
__global__ void pack_kernel(const float* __restrict__ S, int ldb, int row0, int col0, int mode,
                            unsigned short* __restrict__ BP) {
    int idx = blockIdx.x * blockDim.x + threadIdx.x;
    if (idx >= PKSZ) return;
    int jj = idx & 7;
    int l = (idx >> 3) & 63;
    int r2 = idx >> 9;             // cf*NKT + kt
    int cf = r2 / NKT, kt = r2 - cf * NKT;
    int k = kt * 32 + ((l >> 4) << 3) + jj;
    int j = cf * 16 + (l & 15);
    float v = 0.0f;
    if (k < HH && j < HH)
        v = mode ? S[(size_t)(row0 + j) * HH + k] : S[(size_t)k * ldb + col0 + j];
    BP[idx] = f2bf(v);
}

__global__ void count_kernel(const int* __restrict__ el, int* __restrict__ cnt) {
    int idx = blockIdx.x * blockDim.x + threadIdx.x;
    if (idx >= NEDG) return;
    int ty = idx / EE, e = idx - ty * EE;
    int2 pr = (ty < 3) ? reinterpret_cast<const int2*>(el)[ty * EE + e]
                       : reinterpret_cast<const int2*>(el)[(ty - 3) * EE + e];
    int tg = (ty < 3) ? pr.y : pr.x;
    atomicAdd(&cnt[tg], 1);
}

__global__ void scan1_kernel(const int* __restrict__ cnt, int* __restrict__ off,
                             int* __restrict__ bsum) {
    __shared__ int sd[256];
    int t = threadIdx.x, i = blockIdx.x * 256 + t;
    int v = (i < NN) ? cnt[i] : 0;
    sd[t] = v;
    __syncthreads();
    for (int s = 1; s < 256; s <<= 1) {
        int u = (t >= s) ? sd[t - s] : 0;
        __syncthreads();
        sd[t] += u;
        __syncthreads();
    }
    if (i < NN) off[i] = sd[t] - v;
    if (t == 255) bsum[blockIdx.x] = sd[255];
}

__global__ void scan2_kernel(int* __restrict__ bsum, int nb) {
    __shared__ int sd[256];
    int t = threadIdx.x;
    int v = (t < nb) ? bsum[t] : 0;
    sd[t] = v;
    __syncthreads();
    for (int s = 1; s < 256; s <<= 1) {
        int u = (t >= s) ? sd[t - s] : 0;
        __syncthreads();
        sd[t] += u;
        __syncthreads();
    }
    if (t < nb) bsum[t] = sd[t] - v;   // exclusive
}

__global__ void scan3_kernel(int* __restrict__ off, const int* __restrict__ bsum,
                             int* __restrict__ cursor) {
    int i = blockIdx.x * 256 + threadIdx.x;
    if (i < NN) {
        int o = off[i] + bsum[blockIdx.x];
        off[i] = o;
        cursor[i] = o;
    }
    if (i == 0) off[NN] = NEDG;
}

__global__ void inv_kernel(const int* __restrict__ cnt, float* __restrict__ inv) {
    int n = blockIdx.x * blockDim.x + threadIdx.x;
    if (n < NN) inv[n] = 1.0f / (float)max(cnt[n], 1);
}

// EDG[slot] = src(17b) << 13 | ty(3b) << 10 | pos(10b), grouped by target via cursor
__global__ void fill_kernel(const int* __restrict__ el, const int* __restrict__ pl,
                            int* __restrict__ cursor, int* __restrict__ edg) {
    int idx = blockIdx.x * blockDim.x + threadIdx.x;
    if (idx >= NEDG) return;
    int ty = idx / EE, e = idx - ty * EE;
    int s, tg;
    if (ty < 3) {
        int2 pr = reinterpret_cast<const int2*>(el)[ty * EE + e];
        s = pr.x; tg = pr.y;
    } else {
        int2 pr = reinterpret_cast<const int2*>(el)[(ty - 3) * EE + e];
        s = pr.y; tg = pr.x;
    }
    int p = pl[(ty % 3) * EE + e];
    p = min(max(p, 0), PMX - 1);
    int slot = atomicAdd(&cursor[tg], 1);
    edg[slot] = (s << 13) | (ty << 10) | p;
}

// chunks[ty][n][j] (bf16), all 6 ty. M=64; 4 waves ROW-split (wave w = rows w*16..+15),
// each wave all 13 col-frags: one ds_read_b128 per kt feeds 13 MFMAs. A staged once in
// fragment-order LDS (lane-contiguous reads, conflict-free). Output via c_lds + linear copy.
__global__ __launch_bounds__(256, 2) void prop_fused(
    const float* __restrict__ A, const unsigned short* __restrict__ BPp,
    const float* __restrict__ msg_b,
    unsigned short* __restrict__ CH0, unsigned short* __restrict__ CH45) {
    __shared__ alignas(16) unsigned short a_lds[AFR];
    __shared__ alignas(16) unsigned short c_lds[64 * HH];
    const int t = threadIdx.x;
    const int w = t >> 6;
    const int l = t & 63;
    const int lm = l & 15, lh = l >> 4;
    const int base = blockIdx.x * 64;
    const int vrows = min(64, NN - base);
    const int nu4 = (vrows * HH * 2) >> 4;   // uint4 count of bf16 tile

    for (int idx = t; idx < 64 * 101; idx += 256) {
        int row = idx / 101;
        int c = idx - row * 101;
        int gn = base + row;
        float2 v = make_float2(0.f, 0.f);
        if (gn < NN) v = *reinterpret_cast<const float2*>(&A[(size_t)gn * HH + c * 2]);
        ushort2 bv; bv.x = f2bf(v.x); bv.y = f2bf(v.y);
        *reinterpret_cast<ushort2*>(&a_lds[frag_off(row, c * 2)]) = bv;
    }
    for (int idx = t; idx < 64 * 11; idx += 256) {
        int row = idx / 11;
        int c = idx - row * 11;
        ushort2 z; z.x = 0; z.y = 0;
        *reinterpret_cast<ushort2*>(&a_lds[frag_off(row, HH + c * 2)]) = z;
    }
    __syncthreads();

#pragma unroll 1
    for (int ty = 0; ty < 6; ++ty) {
        const unsigned short* BP = BPp + (size_t)ty * PKSZ;
        v4f acc[13];
#pragma unroll
        for (int cf = 0; cf < 13; ++cf) acc[cf] = (v4f){0.f, 0.f, 0.f, 0.f};

#pragma unroll 1
        for (int kt = 0; kt < NKT; ++kt) {
            short8 a = *reinterpret_cast<const short8*>(&a_lds[((w * NKT + kt) * 64 + l) * 8]);
#pragma unroll
            for (int cf = 0; cf < 13; ++cf) {
                short8 b = *reinterpret_cast<const short8*>(
                    &BP[((size_t)(cf * NKT + kt) * 64 + l) * 8]);
                acc[cf] = __builtin_amdgcn_mfma_f32_16x16x32_bf16(a, b, acc[cf], 0, 0, 0);
            }
        }

        __syncthreads();   // prior ty's copy-out done before c_lds overwrite
#pragma unroll
        for (int cf = 0; cf < 13; ++cf) {
            int col = cf * 16 + lm;
            if (col < HH) {
                float bb = msg_b[ty * HH + col];
#pragma unroll
                for (int r = 0; r < 4; ++r)
                    c_lds[(w * 16 + lh * 4 + r) * HH + col] = f2bf(acc[cf][r] + bb);
            }
        }
        __syncthreads();

        unsigned short* CH = (ty < 4) ? CH0 + (size_t)ty * NN * HH
                                      : CH45 + (size_t)(ty - 4) * NN * HH;
        uint4* dst = reinterpret_cast<uint4*>(CH + (size_t)base * HH);
        const uint4* srcp = reinterpret_cast<const uint4*>(c_lds);
        for (int i = t; i < nu4; i += 256) dst[i] = srcp[i];
    }
}

// one wave per target node: MSG[n] (bf16) = inv[n] * sum_edges chunk[ty][src] * gate[pos]
__global__ void agg_kernel(const unsigned short* __restrict__ CH0,
                           const unsigned short* __restrict__ CH45,
                           const int* __restrict__ off, const int* __restrict__ edg,
                           const unsigned short* __restrict__ gate,
                           const float* __restrict__ inv, unsigned short* __restrict__ msgb) {
    int n = blockIdx.x * 4 + (threadIdx.x >> 6);
    if (n >= NN) return;
    int lane = threadIdx.x & 63;
    int s0 = off[n], s1 = off[n + 1];
    int j0 = lane, j1 = lane + 64, j2 = lane + 128, j3 = lane + 192;
    bool j3ok = j3 < HH;
    float a0 = 0.f, a1 = 0.f, a2 = 0.f, a3 = 0.f;
    float b0 = 0.f, b1 = 0.f, b2 = 0.f, b3 = 0.f;
    int i = s0;
    for (; i + 1 < s1; i += 2) {
        int recA = edg[i], recB = edg[i + 1];
        int sA = recA >> 13, tyA = (recA >> 10) & 7, pA = recA & 1023;
        int sB = recB >> 13, tyB = (recB >> 10) & 7, pB = recB & 1023;
        const unsigned short* crA =
            ((tyA < 4) ? CH0 + (size_t)tyA * NN * HH : CH45 + (size_t)(tyA - 4) * NN * HH)
            + (size_t)sA * HH;
        const unsigned short* crB =
            ((tyB < 4) ? CH0 + (size_t)tyB * NN * HH : CH45 + (size_t)(tyB - 4) * NN * HH)
            + (size_t)sB * HH;
        const unsigned short* grA = gate + (size_t)pA * HH;
        const unsigned short* grB = gate + (size_t)pB * HH;
        a0 += bf2f(crA[j0]) * bf2f(grA[j0]);
        b0 += bf2f(crB[j0]) * bf2f(grB[j0]);
        a1 += bf2f(crA[j1]) * bf2f(grA[j1]);
        b1 += bf2f(crB[j1]) * bf2f(grB[j1]);
        a2 += bf2f(crA[j2]) * bf2f(grA[j2]);
        b2 += bf2f(crB[j2]) * bf2f(grB[j2]);
        if (j3ok) { a3 += bf2f(crA[j3]) * bf2f(grA[j3]);
                    b3 += bf2f(crB[j3]) * bf2f(grB[j3]); }
    }
    if (i < s1) {
        int rec = edg[i];
        int src = rec >> 13, ty = (rec >> 10) & 7, p = rec & 1023;
        const unsigned short* cr =
            ((ty < 4) ? CH0 + (size_t)ty * NN * HH : CH45 + (size_t)(ty - 4) * NN * HH)
            + (size_t)src * HH;
        const unsigned short* gr = gate + (size_t)p * HH;
        a0 += bf2f(cr[j0]) * bf2f(gr[j0]);
        a1 += bf2f(cr[j1]) * bf2f(gr[j1]);
        a2 += bf2f(cr[j2]) * bf2f(gr[j2]);
        if (j3ok) a3 += bf2f(cr[j3]) * bf2f(gr[j3]);
    }
    float iv = inv[n];
    unsigned short* mr = msgb + (size_t)n * HH;
    mr[j0] = f2bf((a0 + b0) * iv); mr[j1] = f2bf((a1 + b1) * iv);
    mr[j2] = f2bf((a2 + b2) * iv);
    if (j3ok) mr[j3] = f2bf((a3 + b3) * iv);
}

// Fused GRU. M=64; 4 waves ROW-split, each wave all 13 col-frags. h & msg snapshotted
// into fragment-order LDS (in-place h update race-free: all GEMM reads from snapshot;
// hv reads precede the barrier-separated staged write-back; waves own disjoint rows).
// Epilogue staged as f32 tile in (reused) LDS -> linear float2 copy-out.
__global__ __launch_bounds__(256, 2) void gru_fused(
    float* h, const float* hsrc, const unsigned short* __restrict__ msgb,
    const unsigned short* __restrict__ BPir, const unsigned short* __restrict__ BPiz,
    const unsigned short* __restrict__ BPin, const unsigned short* __restrict__ BPhr,
    const unsigned short* __restrict__ BPhz, const unsigned short* __restrict__ BPhn,
    const float* __restrict__ bih, const float* __restrict__ bhh) {
    __shared__ alignas(16) unsigned short smem[2 * AFR];   // hl | ml ; reused as f32 out-tile
    unsigned short* hl = smem;
    unsigned short* ml = smem + AFR;
    const int t = threadIdx.x;
    const int w = t >> 6;
    const int l = t & 63;
    const int lm = l & 15, lh = l >> 4;
    const int base = blockIdx.x * 64;
    const int vrows = min(64, NN - base);

    for (int idx = t; idx < 64 * 101; idx += 256) {
        int row = idx / 101;
        int c = idx - row * 101;
        int gn = base + row;
        float2 vh = make_float2(0.f, 0.f);
        ushort2 vm; vm.x = 0; vm.y = 0;
        if (gn < NN) {
            vh = *reinterpret_cast<const float2*>(&hsrc[(size_t)gn * HH + c * 2]);
            vm = *reinterpret_cast<const ushort2*>(&msgb[(size_t)gn * HH + c * 2]);
        }
        ushort2 bh; bh.x = f2bf(vh.x); bh.y = f2bf(vh.y);
        int fo = frag_off(row, c * 2);
        *reinterpret_cast<ushort2*>(&hl[fo]) = bh;
        *reinterpret_cast<ushort2*>(&ml[fo]) = vm;
    }
    for (int idx = t; idx < 64 * 11; idx += 256) {
        int row = idx / 11;
        int c = idx - row * 11;
        ushort2 z; z.x = 0; z.y = 0;
        int fo = frag_off(row, HH + c * 2);
        *reinterpret_cast<ushort2*>(&hl[fo]) = z;
        *reinterpret_cast<ushort2*>(&ml[fo]) = z;
    }
    __syncthreads();

    v4f P1[13], P2[13];
#pragma unroll
    for (int cf = 0; cf < 13; ++cf) P1[cf] = (v4f){0.f, 0.f, 0.f, 0.f};

    // loop 1: P1 = msg@Wir + h@Whr
#pragma unroll 1
    for (int kt = 0; kt < NKT; ++kt) {
        int ao = ((w * NKT + kt) * 64 + l) * 8;
        short8 ah = *reinterpret_cast<const short8*>(&hl[ao]);
        short8 am = *reinterpret_cast<const short8*>(&ml[ao]);
#pragma unroll
        for (int cf = 0; cf < 13; ++cf) {
            size_t bo = ((size_t)(cf * NKT + kt) * 64 + l) * 8;
            short8 bir = *reinterpret_cast<const short8*>(&BPir[bo]);
            short8 bhr = *reinterpret_cast<const short8*>(&BPhr[bo]);
            P1[cf] = __builtin_amdgcn_mfma_f32_16x16x32_bf16(am, bir, P1[cf], 0, 0, 0);
            P1[cf] = __builtin_amdgcn_mfma_f32_16x16x32_bf16(ah, bhr, P1[cf], 0, 0, 0);
        }
    }
    // r = sig(P1 + br)
#pragma unroll
    for (int cf = 0; cf < 13; ++cf) {
        int col = cf * 16 + lm;
        float br = (col < HH) ? (bih[col] + bhh[col]) : 0.f;
#pragma unroll
        for (int r = 0; r < 4; ++r) P1[cf][r] = sigf(P1[cf][r] + br);
    }

    // loop 2: P2 = h@Whn
#pragma unroll
    for (int cf = 0; cf < 13; ++cf) P2[cf] = (v4f){0.f, 0.f, 0.f, 0.f};
#pragma unroll 1
    for (int kt = 0; kt < NKT; ++kt) {
        int ao = ((w * NKT + kt) * 64 + l) * 8;
        short8 ah = *reinterpret_cast<const short8*>(&hl[ao]);
#pragma unroll
        for (int cf = 0; cf < 13; ++cf) {
            size_t bo = ((size_t)(cf * NKT + kt) * 64 + l) * 8;
            short8 bhn = *reinterpret_cast<const short8*>(&BPhn[bo]);
            P2[cf] = __builtin_amdgcn_mfma_f32_16x16x32_bf16(ah, bhn, P2[cf], 0, 0, 0);
        }
    }
    // P2 = bin + r*(P2 + bnh)
#pragma unroll
    for (int cf = 0; cf < 13; ++cf) {
        int col = cf * 16 + lm;
        float bn_i = (col < HH) ? bih[404 + col] : 0.f;
        float bn_h = (col < HH) ? bhh[404 + col] : 0.f;
#pragma unroll
        for (int r = 0; r < 4; ++r) P2[cf][r] = bn_i + P1[cf][r] * (P2[cf][r] + bn_h);
    }

    // loop 3: P2 += msg@Win; then n = tanh(P2)
#pragma unroll 1
    for (int kt = 0; kt < NKT; ++kt) {
        int ao = ((w * NKT + kt) * 64 + l) * 8;
        short8 am = *reinterpret_cast<const short8*>(&ml[ao]);
#pragma unroll
        for (int cf = 0; cf < 13; ++cf) {
            size_t bo = ((size_t)(cf * NKT + kt) * 64 + l) * 8;
            short8 bin_ = *reinterpret_cast<const short8*>(&BPin[bo]);
            P2[cf] = __builtin_amdgcn_mfma_f32_16x16x32_bf16(am, bin_, P2[cf], 0, 0, 0);
        }
    }
#pragma unroll
    for (int cf = 0; cf < 13; ++cf)
#pragma unroll
        for (int r = 0; r < 4; ++r) P2[cf][r] = tanhf(P2[cf][r]);

    // loop 4: P1 = msg@Wiz + h@Whz
#pragma unroll
    for (int cf = 0; cf < 13; ++cf) P1[cf] = (v4f){0.f, 0.f, 0.f, 0.f};
#pragma unroll 1
    for (int kt = 0; kt < NKT; ++kt) {
        int ao = ((w * NKT + kt) * 64 + l) * 8;
        short8 ah = *reinterpret_cast<const short8*>(&hl[ao]);
        short8 am = *reinterpret_cast<const short8*>(&ml[ao]);
#pragma unroll
        for (int cf = 0; cf < 13; ++cf) {
            size_t bo = ((size_t)(cf * NKT + kt) * 64 + l) * 8;
            short8 biz = *reinterpret_cast<const short8*>(&BPiz[bo]);
            short8 bhz = *reinterpret_cast<const short8*>(&BPhz[bo]);
            P1[cf] = __builtin_amdgcn_mfma_f32_16x16x32_bf16(am, biz, P1[cf], 0, 0, 0);
            P1[cf] = __builtin_amdgcn_mfma_f32_16x16x32_bf16(ah, bhz, P1[cf], 0, 0, 0);
        }
    }

    // z = sig(P1+bz); h' = (1-z)*n + z*hv   (hv from hsrc: own rows, pre-barrier)
    float hp[13][4];
#pragma unroll
    for (int cf = 0; cf < 13; ++cf) {
        int col = cf * 16 + lm;
        if (col < HH) {
            float bz = bih[202 + col] + bhh[202 + col];
#pragma unroll
            for (int r = 0; r < 4; ++r) {
                int row = base + w * 16 + lh * 4 + r;
                float z = sigf(P1[cf][r] + bz);
                float hv = (row < NN) ? hsrc[(size_t)row * HH + col] : 0.f;
                hp[cf][r] = (1.0f - z) * P2[cf][r] + z * hv;
            }
        }
    }

    __syncthreads();   // all LDS fragment reads + hv reads done
    float* cf32 = reinterpret_cast<float*>(smem);   // 64*202 f32 = 51.7KB <= 57.3KB
#pragma unroll
    for (int cf = 0; cf < 13; ++cf) {
        int col = cf * 16 + lm;
        if (col < HH) {
#pragma unroll
            for (int r = 0; r < 4; ++r)
                cf32[(w * 16 + lh * 4 + r) * HH + col] = hp[cf][r];
        }
    }
    __syncthreads();

    float2* dst = reinterpret_cast<float2*>(h + (size_t)base * HH);
    const float2* srcp = reinterpret_cast<const float2*>(cf32);
    const int n2 = vrows * 101;
    for (int i = t; i < n2; i += 256) dst[i] = srcp[i];
}

extern "C" void kernel_launch(void* const* d_in, const int* in_sizes, int n_in,
                              void* d_out, int out_size, void* d_ws, size_t ws_size,
                              hipStream_t stream) {
    const float* node_states = (const float*)d_in[0];
    const int*   el          = (const int*)d_in[1];
    const int*   pl          = (const int*)d_in[2];
    const float* msg_W       = (const float*)d_in[3];
    const float* msg_b       = (const float*)d_in[4];
    const float* pos_W       = (const float*)d_in[5];
    const float* pos_b       = (const float*)d_in[6];
    const float* gWih        = (const float*)d_in[7];
    const float* gWhh        = (const float*)d_in[8];
    const float* gbih        = (const float*)d_in[9];
    const float* gbhh        = (const float*)d_in[10];

    float* out  = (float*)d_out;
    float* h    = out;                               // [N,H] final h
    float* out2 = out + (size_t)NN * HH;             // chunks ty=4,5 during steps; node_states at end

    unsigned short* CH0  = (unsigned short*)d_ws;                    // 4 slabs bf16 [N,H]
    unsigned short* CH45 = (unsigned short*)out2;                    // 2 slabs bf16 [N,H]
    unsigned short* MSGB = CH0 + (size_t)4 * NN * HH;                // [N,H] bf16
    unsigned short* GATE = MSGB + (size_t)NN * HH;                   // [1024,H] bf16
    float* INV  = (float*)(GATE + (size_t)PMX * HH + 8);             // [N]
    int* CNT    = (int*)(INV + NN);                                  // [N]
    int* OFF    = CNT + NN;                                          // [N+4]
    int* CUR    = OFF + NN + 4;                                      // [N]
    int* BS     = CUR + NN;                                          // [256]
    int* EDG    = BS + 256;                                          // [600000]
    unsigned short* BPA = (unsigned short*)(EDG + NEDG);             // 12 packs
    unsigned short* BPp  = BPA;
    unsigned short* BPir = BPA + (size_t)6 * PKSZ;
    unsigned short* BPiz = BPA + (size_t)7 * PKSZ;
    unsigned short* BPin = BPA + (size_t)8 * PKSZ;
    unsigned short* BPhr = BPA + (size_t)9 * PKSZ;
    unsigned short* BPhz = BPA + (size_t)10 * PKSZ;
    unsigned short* BPhn = BPA + (size_t)11 * PKSZ;

    const size_t NH = (size_t)NN * HH;
    hipMemsetAsync(CNT, 0, NN * sizeof(int), stream);
    gate_kernel<<<PMX, 256, 0, stream>>>(pos_W, pos_b, GATE);
    const int pkb = (PKSZ + 255) / 256;
    for (int ty = 0; ty < 6; ++ty)
        pack_kernel<<<pkb, 256, 0, stream>>>(msg_W, 1212, 0, ty * HH, 0, BPp + (size_t)ty * PKSZ);
    pack_kernel<<<pkb, 256, 0, stream>>>(gWih, 0, 0,   0, 1, BPir);
    pack_kernel<<<pkb, 256, 0, stream>>>(gWih, 0, 202, 0, 1, BPiz);
    pack_kernel<<<pkb, 256, 0, stream>>>(gWih, 0, 404, 0, 1, BPin);
    pack_kernel<<<pkb, 256, 0, stream>>>(gWhh, 0, 0,   0, 1, BPhr);
    pack_kernel<<<pkb, 256, 0, stream>>>(gWhh, 0, 202, 0, 1, BPhz);
    pack_kernel<<<pkb, 256, 0, stream>>>(gWhh, 0, 404, 0, 1, BPhn);

    const int nsb = (NN + 255) / 256;    // 196
    count_kernel<<<(NEDG + 255) / 256, 256, 0, stream>>>(el, CNT);
    scan1_kernel<<<nsb, 256, 0, stream>>>(CNT, OFF, BS);
    scan2_kernel<<<1, 256, 0, stream>>>(BS, nsb);
    scan3_kernel<<<nsb, 256, 0, stream>>>(OFF, BS, CUR);
    inv_kernel<<<nsb, 256, 0, stream>>>(CNT, INV);
    fill_kernel<<<(NEDG + 255) / 256, 256, 0, stream>>>(el, pl, CUR, EDG);

    const int gblocks = (NN + 63) / 64;  // 782
    for (int step = 0; step < 2; ++step) {
        const float* hsrc = (step == 0) ? node_states : h;
        prop_fused<<<gblocks, 256, 0, stream>>>(hsrc, BPp, msg_b, CH0, CH45);
        agg_kernel<<<(NN + 3) / 4, 256, 0, stream>>>(CH0, CH45, OFF, EDG, GATE, INV, MSGB);
        gru_fused<<<gblocks, 256, 0, stream>>>(h, hsrc, MSGB, BPir, BPiz, BPin,
                                               BPhr, BPhz, BPhn, gbih, gbhh);
    }
    hipMemcpyAsync(out2, node_states, NH * sizeof(float), hipMemcpyDeviceToDevice, stream);
}

// Round 10
// 777.877 us; speedup vs baseline: 1.7128x; 1.7128x over previous
//
#include <hip/hip_runtime.h>

#define NN 50000
#define HH 202
#define EE 100000
#define PMX 1024
#define NKT 7          // k-steps of 32 (K padded to 224; B packs zero-padded)
#define PKSZ (13 * NKT * 64 * 8)   // ushorts per B pack = 46592
#define NEDG (6 * EE)
#define AFR (4 * NKT * 64 * 8)     // ushorts per fragment-order A tile = 14336

typedef __attribute__((ext_vector_type(8))) short short8;
typedef __attribute__((ext_vector_type(4))) float v4f;

__device__ __forceinline__ float sigf(float x) { return 1.0f / (1.0f + expf(-x)); }

__device__ __forceinline__ unsigned short f2bf(float x) {
    unsigned int u = __float_as_uint(x);
    unsigned int r = (u + 0x7fffu + ((u >> 16) & 1u)) >> 16;
    return (unsigned short)r;
}
__device__ __forceinline__ float bf2f(unsigned short u) {
    return __uint_as_float(((unsigned int)u) << 16);
}

// fragment-order LDS offset for element (row in [0,64), even k in [0,224)):
// slice rf=row>>4; within slice: [kt][lane=(k>>3&3)*16+(row&15)][j=k&7]
__device__ __forceinline__ int frag_off(int row, int k) {
    return (((row >> 4) * NKT + (k >> 5)) * 64 + ((k >> 3) & 3) * 16 + (row & 15)) * 8 + (k & 7);
}

// gate[p][j] = bf16( 2*sigmoid(sum_k pt[p][k]*pos_W[k][j] + pos_b[j]) )
__global__ void gate_kernel(const float* __restrict__ pos_W, const float* __restrict__ pos_b,
                            unsigned short* __restrict__ gate) {
    int p = blockIdx.x;
    __shared__ float pt[HH];
    int t = threadIdx.x;
    if (t < HH) {
        float v;
        if (t < 101) {
            float invf = expf(-(2.0f * t / 202.0f) * 9.210340371976184f); // ln(10000)
            v = sinf((float)p * invf);
        } else {
            int k = t - 101;
            float invf = expf(-(2.0f * k / 202.0f) * 9.210340371976184f);
            v = cosf((float)p * invf);
        }
        pt[t] = v;
    }
    __syncthreads();
    for (int j = t; j < HH; j += blockDim.x) {
        float acc = pos_b[j];
        for (int k = 0; k < HH; ++k) acc += pt[k] * pos_W[k * HH + j];
        gate[p * HH + j] = f2bf(2.0f * sigf(acc));
    }
}

// Pack B into MFMA fragment order, f32 -> bf16 (zeros for k or j >= 202).
__global__ void pack_kernel(const float* __restrict__ S, int ldb, int row0, int col0, int mode,
                            unsigned short* __restrict__ BP) {
    int idx = blockIdx.x * blockDim.x + threadIdx.x;
    if (idx >= PKSZ) return;
    int jj = idx & 7;
    int l = (idx >> 3) & 63;
    int r2 = idx >> 9;             // cf*NKT + kt
    int cf = r2 / NKT, kt = r2 - cf * NKT;
    int k = kt * 32 + ((l >> 4) << 3) + jj;
    int j = cf * 16 + (l & 15);
    float v = 0.0f;
    if (k < HH && j < HH)
        v = mode ? S[(size_t)(row0 + j) * HH + k] : S[(size_t)k * ldb + col0 + j];
    BP[idx] = f2bf(v);
}

__global__ void count_kernel(const int* __restrict__ el, int* __restrict__ cnt) {
    int idx = blockIdx.x * blockDim.x + threadIdx.x;
    if (idx >= NEDG) return;
    int ty = idx / EE, e = idx - ty * EE;
    int2 pr = (ty < 3) ? reinterpret_cast<const int2*>(el)[ty * EE + e]
                       : reinterpret_cast<const int2*>(el)[(ty - 3) * EE + e];
    int tg = (ty < 3) ? pr.y : pr.x;
    atomicAdd(&cnt[tg], 1);
}

__global__ void scan1_kernel(const int* __restrict__ cnt, int* __restrict__ off,
                             int* __restrict__ bsum) {
    __shared__ int sd[256];
    int t = threadIdx.x, i = blockIdx.x * 256 + t;
    int v = (i < NN) ? cnt[i] : 0;
    sd[t] = v;
    __syncthreads();
    for (int s = 1; s < 256; s <<= 1) {
        int u = (t >= s) ? sd[t - s] : 0;
        __syncthreads();
        sd[t] += u;
        __syncthreads();
    }
    if (i < NN) off[i] = sd[t] - v;
    if (t == 255) bsum[blockIdx.x] = sd[255];
}

__global__ void scan2_kernel(int* __restrict__ bsum, int nb) {
    __shared__ int sd[256];
    int t = threadIdx.x;
    int v = (t < nb) ? bsum[t] : 0;
    sd[t] = v;
    __syncthreads();
    for (int s = 1; s < 256; s <<= 1) {
        int u = (t >= s) ? sd[t - s] : 0;
        __syncthreads();
        sd[t] += u;
        __syncthreads();
    }
    if (t < nb) bsum[t] = sd[t] - v;   // exclusive
}

__global__ void scan3_kernel(int* __restrict__ off, const int* __restrict__ bsum,
                             int* __restrict__ cursor) {
    int i = blockIdx.x * 256 + threadIdx.x;
    if (i < NN) {
        int o = off[i] + bsum[blockIdx.x];
        off[i] = o;
        cursor[i] = o;
    }
    if (i == 0) off[NN] = NEDG;
}

__global__ void inv_kernel(const int* __restrict__ cnt, float* __restrict__ inv) {
    int n = blockIdx.x * blockDim.x + threadIdx.x;
    if (n < NN) inv[n] = 1.0f / (float)max(cnt[n], 1);
}

// EDG[slot] = src(17b) << 13 | ty(3b) << 10 | pos(10b), grouped by target via cursor
__global__ void fill_kernel(const int* __restrict__ el, const int* __restrict__ pl,
                            int* __restrict__ cursor, int* __restrict__ edg) {
    int idx = blockIdx.x * blockDim.x + threadIdx.x;
    if (idx >= NEDG) return;
    int ty = idx / EE, e = idx - ty * EE;
    int s, tg;
    if (ty < 3) {
        int2 pr = reinterpret_cast<const int2*>(el)[ty * EE + e];
        s = pr.x; tg = pr.y;
    } else {
        int2 pr = reinterpret_cast<const int2*>(el)[(ty - 3) * EE + e];
        s = pr.y; tg = pr.x;
    }
    int p = pl[(ty % 3) * EE + e];
    p = min(max(p, 0), PMX - 1);
    int slot = atomicAdd(&cursor[tg], 1);
    edg[slot] = (s << 13) | (ty << 10) | p;
}

// Shared multi-pack GEMM: O[p] = A @ B[p] (+ bias[p]), bf16 out.
// M=64/block, 512 threads = 8 waves: 2 row-groups (32 rows, 2 rf) x 4 col-groups
// ({4,3,3,3} cfs). A staged once in fragment-order LDS (lane-contiguous ds_read_b128,
// conflict-free); per kt: 2 A-reads feed up to 8 MFMAs; each B frag read by 2 waves
// (L2-resident packs). Output staged in c_lds -> linear uint4 coalesced copy-out.
// Slab p goes to O0+p*NH if p<split else O1+(p-split)*NH.
__global__ __launch_bounds__(512, 4) void gemm9(
    const void* __restrict__ Asrc, int a_is_f32,
    const unsigned short* __restrict__ BPbase, int npack,
    const float* __restrict__ bias,
    unsigned short* __restrict__ O0, unsigned short* __restrict__ O1, int split) {
    __shared__ alignas(16) unsigned short a_lds[AFR];
    __shared__ alignas(16) unsigned short c_lds[64 * HH];
    const int t = threadIdx.x;
    const int w = t >> 6;
    const int l = t & 63;
    const int lm = l & 15, lh = l >> 4;
    const int rowg = w >> 2, colg = w & 3;
    const int cs = colg * 3 + (colg > 0);   // 0,4,7,10
    const int ncf = colg ? 3 : 4;
    const int base = blockIdx.x * 64;
    const int vrows = min(64, NN - base);
    const int nu4 = (vrows * 101) >> 2;     // uint4 per bf16 out tile

    if (a_is_f32) {
        const float* A = (const float*)Asrc;
        for (int idx = t; idx < 64 * 101; idx += 512) {
            int row = idx / 101;
            int c = idx - row * 101;
            int gn = base + row;
            float2 v = make_float2(0.f, 0.f);
            if (gn < NN) v = *reinterpret_cast<const float2*>(&A[(size_t)gn * HH + c * 2]);
            ushort2 bv; bv.x = f2bf(v.x); bv.y = f2bf(v.y);
            *reinterpret_cast<ushort2*>(&a_lds[frag_off(row, c * 2)]) = bv;
        }
    } else {
        const unsigned short* A = (const unsigned short*)Asrc;
        for (int idx = t; idx < 64 * 101; idx += 512) {
            int row = idx / 101;
            int c = idx - row * 101;
            int gn = base + row;
            ushort2 v; v.x = 0; v.y = 0;
            if (gn < NN) v = *reinterpret_cast<const ushort2*>(&A[(size_t)gn * HH + c * 2]);
            *reinterpret_cast<ushort2*>(&a_lds[frag_off(row, c * 2)]) = v;
        }
    }
    for (int idx = t; idx < 64 * 11; idx += 512) {
        int row = idx / 11;
        int c = idx - row * 11;
        ushort2 z; z.x = 0; z.y = 0;
        *reinterpret_cast<ushort2*>(&a_lds[frag_off(row, HH + c * 2)]) = z;
    }
    __syncthreads();

    const int aslice = (rowg * 2) * (NKT * 64 * 8);   // rf slices 2*rowg, 2*rowg+1

#pragma unroll 1
    for (int p = 0; p < npack; ++p) {
        const unsigned short* BP = BPbase + (size_t)p * PKSZ;
        v4f acc[4][2];
#pragma unroll
        for (int ci = 0; ci < 4; ++ci) {
            acc[ci][0] = (v4f){0.f, 0.f, 0.f, 0.f};
            acc[ci][1] = (v4f){0.f, 0.f, 0.f, 0.f};
        }

#pragma unroll 1
        for (int kt = 0; kt < NKT; ++kt) {
            int ao = aslice + (kt * 64 + l) * 8;
            short8 a0 = *reinterpret_cast<const short8*>(&a_lds[ao]);
            short8 a1 = *reinterpret_cast<const short8*>(&a_lds[ao + NKT * 64 * 8]);
#pragma unroll
            for (int ci = 0; ci < 4; ++ci) {
                if (ci < ncf) {
                    short8 b = *reinterpret_cast<const short8*>(
                        &BP[((size_t)((cs + ci) * NKT + kt) * 64 + l) * 8]);
                    acc[ci][0] = __builtin_amdgcn_mfma_f32_16x16x32_bf16(a0, b, acc[ci][0], 0, 0, 0);
                    acc[ci][1] = __builtin_amdgcn_mfma_f32_16x16x32_bf16(a1, b, acc[ci][1], 0, 0, 0);
                }
            }
        }

        __syncthreads();   // prior pack's copy-out complete before c_lds overwrite
#pragma unroll
        for (int ci = 0; ci < 4; ++ci) {
            if (ci < ncf) {
                int col = (cs + ci) * 16 + lm;
                if (col < HH) {
                    float bb = bias ? bias[p * HH + col] : 0.0f;
#pragma unroll
                    for (int rfi = 0; rfi < 2; ++rfi) {
#pragma unroll
                        for (int r = 0; r < 4; ++r)
                            c_lds[(rowg * 32 + rfi * 16 + lh * 4 + r) * HH + col] =
                                f2bf(acc[ci][rfi][r] + bb);
                    }
                }
            }
        }
        __syncthreads();

        unsigned short* slab = (p < split) ? O0 + (size_t)p * NN * HH
                                           : O1 + (size_t)(p - split) * NN * HH;
        uint4* dst = reinterpret_cast<uint4*>(slab + (size_t)base * HH);
        const uint4* srcp = reinterpret_cast<const uint4*>(c_lds);
        for (int i = t; i < nu4; i += 512) dst[i] = srcp[i];
    }
}

// one wave per target node: MSG[n] (bf16) = inv[n] * sum_edges chunk[ty][src] * gate[pos]
__global__ void agg_kernel(const unsigned short* __restrict__ CH0,
                           const unsigned short* __restrict__ CH45,
                           const int* __restrict__ off, const int* __restrict__ edg,
                           const unsigned short* __restrict__ gate,
                           const float* __restrict__ inv, unsigned short* __restrict__ msgb) {
    int n = blockIdx.x * 4 + (threadIdx.x >> 6);
    if (n >= NN) return;
    int lane = threadIdx.x & 63;
    int s0 = off[n], s1 = off[n + 1];
    int j0 = lane, j1 = lane + 64, j2 = lane + 128, j3 = lane + 192;
    bool j3ok = j3 < HH;
    float a0 = 0.f, a1 = 0.f, a2 = 0.f, a3 = 0.f;
    float b0 = 0.f, b1 = 0.f, b2 = 0.f, b3 = 0.f;
    int i = s0;
    for (; i + 1 < s1; i += 2) {
        int recA = edg[i], recB = edg[i + 1];
        int sA = recA >> 13, tyA = (recA >> 10) & 7, pA = recA & 1023;
        int sB = recB >> 13, tyB = (recB >> 10) & 7, pB = recB & 1023;
        const unsigned short* crA =
            ((tyA < 4) ? CH0 + (size_t)tyA * NN * HH : CH45 + (size_t)(tyA - 4) * NN * HH)
            + (size_t)sA * HH;
        const unsigned short* crB =
            ((tyB < 4) ? CH0 + (size_t)tyB * NN * HH : CH45 + (size_t)(tyB - 4) * NN * HH)
            + (size_t)sB * HH;
        const unsigned short* grA = gate + (size_t)pA * HH;
        const unsigned short* grB = gate + (size_t)pB * HH;
        a0 += bf2f(crA[j0]) * bf2f(grA[j0]);
        b0 += bf2f(crB[j0]) * bf2f(grB[j0]);
        a1 += bf2f(crA[j1]) * bf2f(grA[j1]);
        b1 += bf2f(crB[j1]) * bf2f(grB[j1]);
        a2 += bf2f(crA[j2]) * bf2f(grA[j2]);
        b2 += bf2f(crB[j2]) * bf2f(grB[j2]);
        if (j3ok) { a3 += bf2f(crA[j3]) * bf2f(grA[j3]);
                    b3 += bf2f(crB[j3]) * bf2f(grB[j3]); }
    }
    if (i < s1) {
        int rec = edg[i];
        int src = rec >> 13, ty = (rec >> 10) & 7, p = rec & 1023;
        const unsigned short* cr =
            ((ty < 4) ? CH0 + (size_t)ty * NN * HH : CH45 + (size_t)(ty - 4) * NN * HH)
            + (size_t)src * HH;
        const unsigned short* gr = gate + (size_t)p * HH;
        a0 += bf2f(cr[j0]) * bf2f(gr[j0]);
        a1 += bf2f(cr[j1]) * bf2f(gr[j1]);
        a2 += bf2f(cr[j2]) * bf2f(gr[j2]);
        if (j3ok) a3 += bf2f(cr[j3]) * bf2f(gr[j3]);
    }
    float iv = inv[n];
    unsigned short* mr = msgb + (size_t)n * HH;
    mr[j0] = f2bf((a0 + b0) * iv); mr[j1] = f2bf((a1 + b1) * iv);
    mr[j2] = f2bf((a2 + b2) * iv);
    if (j3ok) mr[j3] = f2bf((a3 + b3) * iv);
}

// Streaming GRU elementwise: one wave per row.
// r = sig(gir+ghr+br); z = sig(giz+ghz+bz); n = tanh(gin+bin + r*(ghn+bnh));
// h' = (1-z)*n + z*hsrc. Same-thread read/write of h -> race-free in-place.
__global__ void gru_ew(float* __restrict__ h, const float* __restrict__ hsrc,
                       const unsigned short* __restrict__ GH,   // 3 slabs: hr,hz,hn
                       const unsigned short* __restrict__ GIr,  // 1 slab
                       const unsigned short* __restrict__ GIzn, // 2 slabs: iz,in
                       const float* __restrict__ bih, const float* __restrict__ bhh) {
    int n = blockIdx.x * 4 + (threadIdx.x >> 6);
    if (n >= NN) return;
    int lane = threadIdx.x & 63;
    const size_t NH = (size_t)NN * HH;
    const size_t ro = (size_t)n * HH;
    for (int j = lane; j < HH; j += 64) {
        float ghr = bf2f(GH[ro + j]);
        float ghz = bf2f(GH[NH + ro + j]);
        float ghn = bf2f(GH[2 * NH + ro + j]);
        float gir = bf2f(GIr[ro + j]);
        float giz = bf2f(GIzn[ro + j]);
        float gin = bf2f(GIzn[NH + ro + j]);
        float r = sigf(gir + ghr + bih[j] + bhh[j]);
        float z = sigf(giz + ghz + bih[202 + j] + bhh[202 + j]);
        float nn = tanhf(gin + bih[404 + j] + r * (ghn + bhh[404 + j]));
        h[ro + j] = (1.0f - z) * nn + z * hsrc[ro + j];
    }
}

extern "C" void kernel_launch(void* const* d_in, const int* in_sizes, int n_in,
                              void* d_out, int out_size, void* d_ws, size_t ws_size,
                              hipStream_t stream) {
    const float* node_states = (const float*)d_in[0];
    const int*   el          = (const int*)d_in[1];
    const int*   pl          = (const int*)d_in[2];
    const float* msg_W       = (const float*)d_in[3];
    const float* msg_b       = (const float*)d_in[4];
    const float* pos_W       = (const float*)d_in[5];
    const float* pos_b       = (const float*)d_in[6];
    const float* gWih        = (const float*)d_in[7];
    const float* gWhh        = (const float*)d_in[8];
    const float* gbih        = (const float*)d_in[9];
    const float* gbhh        = (const float*)d_in[10];

    float* out  = (float*)d_out;
    float* h    = out;                               // [N,H] final h
    float* out2 = out + (size_t)NN * HH;             // 2 bf16 slabs during steps; node_states at end

    unsigned short* CH0  = (unsigned short*)d_ws;                    // 4 slabs bf16 [N,H]
    unsigned short* CH45 = (unsigned short*)out2;                    // 2 slabs bf16 [N,H]
    unsigned short* MSGB = CH0 + (size_t)4 * NN * HH;                // [N,H] bf16
    unsigned short* GATE = MSGB + (size_t)NN * HH;                   // [1024,H] bf16
    float* INV  = (float*)(GATE + (size_t)PMX * HH + 8);             // [N]
    int* CNT    = (int*)(INV + NN);                                  // [N]
    int* OFF    = CNT + NN;                                          // [N+4]
    int* CUR    = OFF + NN + 4;                                      // [N]
    int* BS     = CUR + NN;                                          // [256]
    int* EDG    = BS + 256;                                          // [600000]
    unsigned short* BPA = (unsigned short*)(EDG + NEDG);             // 12 packs
    unsigned short* BPp  = BPA;                                      // 6 prop packs
    unsigned short* BPih = BPA + (size_t)6 * PKSZ;                   // ir,iz,in (contig)
    unsigned short* BPhh = BPA + (size_t)9 * PKSZ;                   // hr,hz,hn (contig)

    const size_t NH = (size_t)NN * HH;
    hipMemsetAsync(CNT, 0, NN * sizeof(int), stream);
    gate_kernel<<<PMX, 256, 0, stream>>>(pos_W, pos_b, GATE);
    const int pkb = (PKSZ + 255) / 256;
    for (int ty = 0; ty < 6; ++ty)
        pack_kernel<<<pkb, 256, 0, stream>>>(msg_W, 1212, 0, ty * HH, 0, BPp + (size_t)ty * PKSZ);
    pack_kernel<<<pkb, 256, 0, stream>>>(gWih, 0, 0,   0, 1, BPih);
    pack_kernel<<<pkb, 256, 0, stream>>>(gWih, 0, 202, 0, 1, BPih + PKSZ);
    pack_kernel<<<pkb, 256, 0, stream>>>(gWih, 0, 404, 0, 1, BPih + 2 * PKSZ);
    pack_kernel<<<pkb, 256, 0, stream>>>(gWhh, 0, 0,   0, 1, BPhh);
    pack_kernel<<<pkb, 256, 0, stream>>>(gWhh, 0, 202, 0, 1, BPhh + PKSZ);
    pack_kernel<<<pkb, 256, 0, stream>>>(gWhh, 0, 404, 0, 1, BPhh + 2 * PKSZ);

    const int nsb = (NN + 255) / 256;    // 196
    count_kernel<<<(NEDG + 255) / 256, 256, 0, stream>>>(el, CNT);
    scan1_kernel<<<nsb, 256, 0, stream>>>(CNT, OFF, BS);
    scan2_kernel<<<1, 256, 0, stream>>>(BS, nsb);
    scan3_kernel<<<nsb, 256, 0, stream>>>(OFF, BS, CUR);
    inv_kernel<<<nsb, 256, 0, stream>>>(CNT, INV);
    fill_kernel<<<(NEDG + 255) / 256, 256, 0, stream>>>(el, pl, CUR, EDG);

    const int gblocks = (NN + 63) / 64;  // 782
    const int ewblocks = (NN + 3) / 4;
    for (int step = 0; step < 2; ++step) {
        const float* hsrc = (step == 0) ? node_states : h;
        // 6 chunk GEMMs from h
        gemm9<<<gblocks, 512, 0, stream>>>(hsrc, 1, BPp, 6, msg_b, CH0, CH45, 4);
        // edge aggregation -> MSGB (bf16)
        agg_kernel<<<ewblocks, 256, 0, stream>>>(CH0, CH45, OFF, EDG, GATE, INV, MSGB);
        // gh{r,z,n} = h @ Whh^T  -> CH0 slabs 0..2 (agg already consumed chunks)
        gemm9<<<gblocks, 512, 0, stream>>>(hsrc, 1, BPhh, 3, nullptr, CH0, nullptr, 4);
        // gi{r,z,n} = msg @ Wih^T -> CH0 slab 3, CH45 slabs 0..1
        gemm9<<<gblocks, 512, 0, stream>>>(MSGB, 0, BPih, 3, nullptr,
                                           CH0 + 3 * NH, CH45, 1);
        // streaming GRU elementwise, in-place h
        gru_ew<<<ewblocks, 256, 0, stream>>>(h, hsrc, CH0, CH0 + 3 * NH, CH45, gbih, gbhh);
    }
    hipMemcpyAsync(out2, node_states, NH * sizeof(float), hipMemcpyDeviceToDevice, stream);
}

// Round 11
// 660.069 us; speedup vs baseline: 2.0185x; 1.1785x over previous
//
#include <hip/hip_runtime.h>

#define NN 50000
#define HH 202
#define EE 100000
#define PMX 1024
#define NKT 7          // k-steps of 32 (K padded to 224; packs zero-padded)
#define PKS2 (16 * NKT * 64 * 8)   // ushorts per padded B pack (16 cf) = 57344
#define NEDG (6 * EE)
#define AFR (4 * NKT * 64 * 8)     // ushorts per fragment-order A tile = 14336

typedef __attribute__((ext_vector_type(8))) short short8;
typedef __attribute__((ext_vector_type(4))) float v4f;

__device__ __forceinline__ float sigf(float x) { return 1.0f / (1.0f + expf(-x)); }

__device__ __forceinline__ unsigned short f2bf(float x) {
    unsigned int u = __float_as_uint(x);
    unsigned int r = (u + 0x7fffu + ((u >> 16) & 1u)) >> 16;
    return (unsigned short)r;
}
__device__ __forceinline__ float bf2f(unsigned short u) {
    return __uint_as_float(((unsigned int)u) << 16);
}

// fragment-order LDS offset for element (row in [0,64), even k in [0,224)):
// slice rf=row>>4; within slice: [kt][lane=(k>>3&3)*16+(row&15)][j=k&7]
__device__ __forceinline__ int frag_off(int row, int k) {
    return (((row >> 4) * NKT + (k >> 5)) * 64 + ((k >> 3) & 3) * 16 + (row & 15)) * 8 + (k & 7);
}

// gate[p][j] = bf16( 2*sigmoid(sum_k pt[p][k]*pos_W[k][j] + pos_b[j]) )
__global__ void gate_kernel(const float* __restrict__ pos_W, const float* __restrict__ pos_b,
                            unsigned short* __restrict__ gate) {
    int p = blockIdx.x;
    __shared__ float pt[HH];
    int t = threadIdx.x;
    if (t < HH) {
        float v;
        if (t < 101) {
            float invf = expf(-(2.0f * t / 202.0f) * 9.210340371976184f); // ln(10000)
            v = sinf((float)p * invf);
        } else {
            int k = t - 101;
            float invf = expf(-(2.0f * k / 202.0f) * 9.210340371976184f);
            v = cosf((float)p * invf);
        }
        pt[t] = v;
    }
    __syncthreads();
    for (int j = t; j < HH; j += blockDim.x) {
        float acc = pos_b[j];
        for (int k = 0; k < HH; ++k) acc += pt[k] * pos_W[k * HH + j];
        gate[p * HH + j] = f2bf(2.0f * sigf(acc));
    }
}

// Pack B into MFMA fragment order (16 cf, padded), f32 -> bf16; zeros for k,j >= 202.
// BP[((cf*NKT + kt)*64 + l)*8 + jj] = B[k][j], k = kt*32+(l>>4)*8+jj, j = cf*16+(l&15)
__global__ void pack_kernel(const float* __restrict__ S, int ldb, int row0, int col0, int mode,
                            unsigned short* __restrict__ BP) {
    int idx = blockIdx.x * blockDim.x + threadIdx.x;
    if (idx >= PKS2) return;
    int jj = idx & 7;
    int l = (idx >> 3) & 63;
    int r2 = idx >> 9;             // cf*NKT + kt, cf in 0..15
    int cf = r2 / NKT, kt = r2 - cf * NKT;
    int k = kt * 32 + ((l >> 4) << 3) + jj;
    int j = cf * 16 + (l & 15);
    float v = 0.0f;
    if (k < HH && j < HH)
        v = mode ? S[(size_t)(row0 + j) * HH + k] : S[(size_t)k * ldb + col0 + j];
    BP[idx] = f2bf(v);
}

__global__ void count_kernel(const int* __restrict__ el, int* __restrict__ cnt) {
    int idx = blockIdx.x * blockDim.x + threadIdx.x;
    if (idx >= NEDG) return;
    int ty = idx / EE, e = idx - ty * EE;
    int2 pr = (ty < 3) ? reinterpret_cast<const int2*>(el)[ty * EE + e]
                       : reinterpret_cast<const int2*>(el)[(ty - 3) * EE + e];
    int tg = (ty < 3) ? pr.y : pr.x;
    atomicAdd(&cnt[tg], 1);
}

__global__ void scan1_kernel(const int* __restrict__ cnt, int* __restrict__ off,
                             int* __restrict__ bsum) {
    __shared__ int sd[256];
    int t = threadIdx.x, i = blockIdx.x * 256 + t;
    int v = (i < NN) ? cnt[i] : 0;
    sd[t] = v;
    __syncthreads();
    for (int s = 1; s < 256; s <<= 1) {
        int u = (t >= s) ? sd[t - s] : 0;
        __syncthreads();
        sd[t] += u;
        __syncthreads();
    }
    if (i < NN) off[i] = sd[t] - v;
    if (t == 255) bsum[blockIdx.x] = sd[255];
}

__global__ void scan2_kernel(int* __restrict__ bsum, int nb) {
    __shared__ int sd[256];
    int t = threadIdx.x;
    int v = (t < nb) ? bsum[t] : 0;
    sd[t] = v;
    __syncthreads();
    for (int s = 1; s < 256; s <<= 1) {
        int u = (t >= s) ? sd[t - s] : 0;
        __syncthreads();
        sd[t] += u;
        __syncthreads();
    }
    if (t < nb) bsum[t] = sd[t] - v;   // exclusive
}

__global__ void scan3_kernel(int* __restrict__ off, const int* __restrict__ bsum,
                             int* __restrict__ cursor) {
    int i = blockIdx.x * 256 + threadIdx.x;
    if (i < NN) {
        int o = off[i] + bsum[blockIdx.x];
        off[i] = o;
        cursor[i] = o;
    }
    if (i == 0) off[NN] = NEDG;
}

__global__ void inv_kernel(const int* __restrict__ cnt, float* __restrict__ inv) {
    int n = blockIdx.x * blockDim.x + threadIdx.x;
    if (n < NN) inv[n] = 1.0f / (float)max(cnt[n], 1);
}

// EDG[slot] = src(17b) << 13 | ty(3b) << 10 | pos(10b), grouped by target via cursor
__global__ void fill_kernel(const int* __restrict__ el, const int* __restrict__ pl,
                            int* __restrict__ cursor, int* __restrict__ edg) {
    int idx = blockIdx.x * blockDim.x + threadIdx.x;
    if (idx >= NEDG) return;
    int ty = idx / EE, e = idx - ty * EE;
    int s, tg;
    if (ty < 3) {
        int2 pr = reinterpret_cast<const int2*>(el)[ty * EE + e];
        s = pr.x; tg = pr.y;
    } else {
        int2 pr = reinterpret_cast<const int2*>(el)[(ty - 3) * EE + e];
        s = pr.y; tg = pr.x;
    }
    int p = pl[(ty % 3) * EE + e];
    p = min(max(p, 0), PMX - 1);
    int slot = atomicAdd(&cursor[tg], 1);
    edg[slot] = (s << 13) | (ty << 10) | p;
}

// Shared multi-pack GEMM: O[p] = A @ B[p] (+ bias[p]), bf16 out.
// M=64/block, 512 threads = 8 waves: 2 row-groups (2 rf) x 4 col-groups (4 cf each,
// packs padded to 16 cf -> branch-free). Fully-unrolled kt loop with 1-deep ping-pong
// prefetch of next-kt A (LDS) and B (L2) fragments -> loads in flight during MFMAs.
// Output staged in c_lds -> linear uint4 coalesced copy-out.
__global__ __launch_bounds__(512, 4) void gemm9(
    const void* __restrict__ Asrc, int a_is_f32,
    const unsigned short* __restrict__ BPbase, int npack,
    const float* __restrict__ bias,
    unsigned short* __restrict__ O0, unsigned short* __restrict__ O1, int split) {
    __shared__ alignas(16) unsigned short a_lds[AFR];
    __shared__ alignas(16) unsigned short c_lds[64 * HH];
    const int t = threadIdx.x;
    const int w = t >> 6;
    const int l = t & 63;
    const int lm = l & 15, lh = l >> 4;
    const int rowg = w >> 2, colg = w & 3;
    const int cs = colg * 4;            // 0,4,8,12
    const int base = blockIdx.x * 64;
    const int vrows = min(64, NN - base);
    const int nu4 = (vrows * 101) >> 2;     // uint4 per bf16 out tile

    if (a_is_f32) {
        const float* A = (const float*)Asrc;
        for (int idx = t; idx < 64 * 101; idx += 512) {
            int row = idx / 101;
            int c = idx - row * 101;
            int gn = base + row;
            float2 v = make_float2(0.f, 0.f);
            if (gn < NN) v = *reinterpret_cast<const float2*>(&A[(size_t)gn * HH + c * 2]);
            ushort2 bv; bv.x = f2bf(v.x); bv.y = f2bf(v.y);
            *reinterpret_cast<ushort2*>(&a_lds[frag_off(row, c * 2)]) = bv;
        }
    } else {
        const unsigned short* A = (const unsigned short*)Asrc;
        for (int idx = t; idx < 64 * 101; idx += 512) {
            int row = idx / 101;
            int c = idx - row * 101;
            int gn = base + row;
            ushort2 v; v.x = 0; v.y = 0;
            if (gn < NN) v = *reinterpret_cast<const ushort2*>(&A[(size_t)gn * HH + c * 2]);
            *reinterpret_cast<ushort2*>(&a_lds[frag_off(row, c * 2)]) = v;
        }
    }
    for (int idx = t; idx < 64 * 11; idx += 512) {
        int row = idx / 11;
        int c = idx - row * 11;
        ushort2 z; z.x = 0; z.y = 0;
        *reinterpret_cast<ushort2*>(&a_lds[frag_off(row, HH + c * 2)]) = z;
    }
    __syncthreads();

    const int aoff0 = (rowg * 2) * (NKT * 512) + l * 8;   // slice 2*rowg, kt=0, lane l
    const int aoff1 = aoff0 + NKT * 512;                  // slice 2*rowg+1

#pragma unroll 1
    for (int p = 0; p < npack; ++p) {
        const unsigned short* BP = BPbase + (size_t)p * PKS2 + (size_t)l * 8;
        v4f acc[4][2];
#pragma unroll
        for (int ci = 0; ci < 4; ++ci) {
            acc[ci][0] = (v4f){0.f, 0.f, 0.f, 0.f};
            acc[ci][1] = (v4f){0.f, 0.f, 0.f, 0.f};
        }

        // prologue: kt=0 fragments
        short8 ac0 = *reinterpret_cast<const short8*>(&a_lds[aoff0]);
        short8 ac1 = *reinterpret_cast<const short8*>(&a_lds[aoff1]);
        short8 bc0 = *reinterpret_cast<const short8*>(BP + (size_t)(cs + 0) * NKT * 512);
        short8 bc1 = *reinterpret_cast<const short8*>(BP + (size_t)(cs + 1) * NKT * 512);
        short8 bc2 = *reinterpret_cast<const short8*>(BP + (size_t)(cs + 2) * NKT * 512);
        short8 bc3 = *reinterpret_cast<const short8*>(BP + (size_t)(cs + 3) * NKT * 512);

#pragma unroll
        for (int kt = 0; kt < NKT; ++kt) {
            const int kn = (kt + 1 < NKT) ? (kt + 1) : kt;   // clamped (last prefetch redundant)
            const int ka = kn * 512;
            short8 an0 = *reinterpret_cast<const short8*>(&a_lds[aoff0 + ka]);
            short8 an1 = *reinterpret_cast<const short8*>(&a_lds[aoff1 + ka]);
            short8 bn0 = *reinterpret_cast<const short8*>(BP + (size_t)(cs + 0) * NKT * 512 + ka);
            short8 bn1 = *reinterpret_cast<const short8*>(BP + (size_t)(cs + 1) * NKT * 512 + ka);
            short8 bn2 = *reinterpret_cast<const short8*>(BP + (size_t)(cs + 2) * NKT * 512 + ka);
            short8 bn3 = *reinterpret_cast<const short8*>(BP + (size_t)(cs + 3) * NKT * 512 + ka);

            acc[0][0] = __builtin_amdgcn_mfma_f32_16x16x32_bf16(ac0, bc0, acc[0][0], 0, 0, 0);
            acc[0][1] = __builtin_amdgcn_mfma_f32_16x16x32_bf16(ac1, bc0, acc[0][1], 0, 0, 0);
            acc[1][0] = __builtin_amdgcn_mfma_f32_16x16x32_bf16(ac0, bc1, acc[1][0], 0, 0, 0);
            acc[1][1] = __builtin_amdgcn_mfma_f32_16x16x32_bf16(ac1, bc1, acc[1][1], 0, 0, 0);
            acc[2][0] = __builtin_amdgcn_mfma_f32_16x16x32_bf16(ac0, bc2, acc[2][0], 0, 0, 0);
            acc[2][1] = __builtin_amdgcn_mfma_f32_16x16x32_bf16(ac1, bc2, acc[2][1], 0, 0, 0);
            acc[3][0] = __builtin_amdgcn_mfma_f32_16x16x32_bf16(ac0, bc3, acc[3][0], 0, 0, 0);
            acc[3][1] = __builtin_amdgcn_mfma_f32_16x16x32_bf16(ac1, bc3, acc[3][1], 0, 0, 0);

            ac0 = an0; ac1 = an1;
            bc0 = bn0; bc1 = bn1; bc2 = bn2; bc3 = bn3;
        }

        __syncthreads();   // prior pack's copy-out complete before c_lds overwrite
#pragma unroll
        for (int ci = 0; ci < 4; ++ci) {
            int col = (cs + ci) * 16 + lm;
            if (col < HH) {
                float bb = bias ? bias[p * HH + col] : 0.0f;
#pragma unroll
                for (int rfi = 0; rfi < 2; ++rfi) {
#pragma unroll
                    for (int r = 0; r < 4; ++r)
                        c_lds[(rowg * 32 + rfi * 16 + lh * 4 + r) * HH + col] =
                            f2bf(acc[ci][rfi][r] + bb);
                }
            }
        }
        __syncthreads();

        unsigned short* slab = (p < split) ? O0 + (size_t)p * NN * HH
                                           : O1 + (size_t)(p - split) * NN * HH;
        uint4* dst = reinterpret_cast<uint4*>(slab + (size_t)base * HH);
        const uint4* srcp = reinterpret_cast<const uint4*>(c_lds);
        for (int i = t; i < nu4; i += 512) dst[i] = srcp[i];
    }
}

// one wave per target node: MSG[n] (bf16) = inv[n] * sum_edges chunk[ty][src] * gate[pos]
__global__ void agg_kernel(const unsigned short* __restrict__ CH0,
                           const unsigned short* __restrict__ CH45,
                           const int* __restrict__ off, const int* __restrict__ edg,
                           const unsigned short* __restrict__ gate,
                           const float* __restrict__ inv, unsigned short* __restrict__ msgb) {
    int n = blockIdx.x * 4 + (threadIdx.x >> 6);
    if (n >= NN) return;
    int lane = threadIdx.x & 63;
    int s0 = off[n], s1 = off[n + 1];
    int j0 = lane, j1 = lane + 64, j2 = lane + 128, j3 = lane + 192;
    bool j3ok = j3 < HH;
    float a0 = 0.f, a1 = 0.f, a2 = 0.f, a3 = 0.f;
    float b0 = 0.f, b1 = 0.f, b2 = 0.f, b3 = 0.f;
    int i = s0;
    for (; i + 1 < s1; i += 2) {
        int recA = edg[i], recB = edg[i + 1];
        int sA = recA >> 13, tyA = (recA >> 10) & 7, pA = recA & 1023;
        int sB = recB >> 13, tyB = (recB >> 10) & 7, pB = recB & 1023;
        const unsigned short* crA =
            ((tyA < 4) ? CH0 + (size_t)tyA * NN * HH : CH45 + (size_t)(tyA - 4) * NN * HH)
            + (size_t)sA * HH;
        const unsigned short* crB =
            ((tyB < 4) ? CH0 + (size_t)tyB * NN * HH : CH45 + (size_t)(tyB - 4) * NN * HH)
            + (size_t)sB * HH;
        const unsigned short* grA = gate + (size_t)pA * HH;
        const unsigned short* grB = gate + (size_t)pB * HH;
        a0 += bf2f(crA[j0]) * bf2f(grA[j0]);
        b0 += bf2f(crB[j0]) * bf2f(grB[j0]);
        a1 += bf2f(crA[j1]) * bf2f(grA[j1]);
        b1 += bf2f(crB[j1]) * bf2f(grB[j1]);
        a2 += bf2f(crA[j2]) * bf2f(grA[j2]);
        b2 += bf2f(crB[j2]) * bf2f(grB[j2]);
        if (j3ok) { a3 += bf2f(crA[j3]) * bf2f(grA[j3]);
                    b3 += bf2f(crB[j3]) * bf2f(grB[j3]); }
    }
    if (i < s1) {
        int rec = edg[i];
        int src = rec >> 13, ty = (rec >> 10) & 7, p = rec & 1023;
        const unsigned short* cr =
            ((ty < 4) ? CH0 + (size_t)ty * NN * HH : CH45 + (size_t)(ty - 4) * NN * HH)
            + (size_t)src * HH;
        const unsigned short* gr = gate + (size_t)p * HH;
        a0 += bf2f(cr[j0]) * bf2f(gr[j0]);
        a1 += bf2f(cr[j1]) * bf2f(gr[j1]);
        a2 += bf2f(cr[j2]) * bf2f(gr[j2]);
        if (j3ok) a3 += bf2f(cr[j3]) * bf2f(gr[j3]);
    }
    float iv = inv[n];
    unsigned short* mr = msgb + (size_t)n * HH;
    mr[j0] = f2bf((a0 + b0) * iv); mr[j1] = f2bf((a1 + b1) * iv);
    mr[j2] = f2bf((a2 + b2) * iv);
    if (j3ok) mr[j3] = f2bf((a3 + b3) * iv);
}

// Streaming GRU elementwise: one wave per row.
// r = sig(gir+ghr+br); z = sig(giz+ghz+bz); n = tanh(gin+bin + r*(ghn+bnh));
// h' = (1-z)*n + z*hsrc. Same-thread read/write of h -> race-free in-place.
__global__ void gru_ew(float* __restrict__ h, const float* __restrict__ hsrc,
                       const unsigned short* __restrict__ GH,   // 3 slabs: hr,hz,hn
                       const unsigned short* __restrict__ GIr,  // 1 slab
                       const unsigned short* __restrict__ GIzn, // 2 slabs: iz,in
                       const float* __restrict__ bih, const float* __restrict__ bhh) {
    int n = blockIdx.x * 4 + (threadIdx.x >> 6);
    if (n >= NN) return;
    int lane = threadIdx.x & 63;
    const size_t NH = (size_t)NN * HH;
    const size_t ro = (size_t)n * HH;
    for (int j = lane; j < HH; j += 64) {
        float ghr = bf2f(GH[ro + j]);
        float ghz = bf2f(GH[NH + ro + j]);
        float ghn = bf2f(GH[2 * NH + ro + j]);
        float gir = bf2f(GIr[ro + j]);
        float giz = bf2f(GIzn[ro + j]);
        float gin = bf2f(GIzn[NH + ro + j]);
        float r = sigf(gir + ghr + bih[j] + bhh[j]);
        float z = sigf(giz + ghz + bih[202 + j] + bhh[202 + j]);
        float nn = tanhf(gin + bih[404 + j] + r * (ghn + bhh[404 + j]));
        h[ro + j] = (1.0f - z) * nn + z * hsrc[ro + j];
    }
}

extern "C" void kernel_launch(void* const* d_in, const int* in_sizes, int n_in,
                              void* d_out, int out_size, void* d_ws, size_t ws_size,
                              hipStream_t stream) {
    const float* node_states = (const float*)d_in[0];
    const int*   el          = (const int*)d_in[1];
    const int*   pl          = (const int*)d_in[2];
    const float* msg_W       = (const float*)d_in[3];
    const float* msg_b       = (const float*)d_in[4];
    const float* pos_W       = (const float*)d_in[5];
    const float* pos_b       = (const float*)d_in[6];
    const float* gWih        = (const float*)d_in[7];
    const float* gWhh        = (const float*)d_in[8];
    const float* gbih        = (const float*)d_in[9];
    const float* gbhh        = (const float*)d_in[10];

    float* out  = (float*)d_out;
    float* h    = out;                               // [N,H] final h
    float* out2 = out + (size_t)NN * HH;             // 2 bf16 slabs during steps; node_states at end

    unsigned short* CH0  = (unsigned short*)d_ws;                    // 4 slabs bf16 [N,H]
    unsigned short* CH45 = (unsigned short*)out2;                    // 2 slabs bf16 [N,H]
    unsigned short* MSGB = CH0 + (size_t)4 * NN * HH;                // [N,H] bf16
    unsigned short* GATE = MSGB + (size_t)NN * HH;                   // [1024,H] bf16
    float* INV  = (float*)(GATE + (size_t)PMX * HH + 8);             // [N]
    int* CNT    = (int*)(INV + NN);                                  // [N]
    int* OFF    = CNT + NN;                                          // [N+4]
    int* CUR    = OFF + NN + 4;                                      // [N]
    int* BS     = CUR + NN;                                          // [256]
    int* EDG    = BS + 256;                                          // [600000]
    unsigned short* BPA = (unsigned short*)(EDG + NEDG);             // 12 padded packs
    unsigned short* BPp  = BPA;                                      // 6 prop packs
    unsigned short* BPih = BPA + (size_t)6 * PKS2;                   // ir,iz,in (contig)
    unsigned short* BPhh = BPA + (size_t)9 * PKS2;                   // hr,hz,hn (contig)

    const size_t NH = (size_t)NN * HH;
    hipMemsetAsync(CNT, 0, NN * sizeof(int), stream);
    gate_kernel<<<PMX, 256, 0, stream>>>(pos_W, pos_b, GATE);
    const int pkb = (PKS2 + 255) / 256;
    for (int ty = 0; ty < 6; ++ty)
        pack_kernel<<<pkb, 256, 0, stream>>>(msg_W, 1212, 0, ty * HH, 0, BPp + (size_t)ty * PKS2);
    pack_kernel<<<pkb, 256, 0, stream>>>(gWih, 0, 0,   0, 1, BPih);
    pack_kernel<<<pkb, 256, 0, stream>>>(gWih, 0, 202, 0, 1, BPih + PKS2);
    pack_kernel<<<pkb, 256, 0, stream>>>(gWih, 0, 404, 0, 1, BPih + 2 * PKS2);
    pack_kernel<<<pkb, 256, 0, stream>>>(gWhh, 0, 0,   0, 1, BPhh);
    pack_kernel<<<pkb, 256, 0, stream>>>(gWhh, 0, 202, 0, 1, BPhh + PKS2);
    pack_kernel<<<pkb, 256, 0, stream>>>(gWhh, 0, 404, 0, 1, BPhh + 2 * PKS2);

    const int nsb = (NN + 255) / 256;    // 196
    count_kernel<<<(NEDG + 255) / 256, 256, 0, stream>>>(el, CNT);
    scan1_kernel<<<nsb, 256, 0, stream>>>(CNT, OFF, BS);
    scan2_kernel<<<1, 256, 0, stream>>>(BS, nsb);
    scan3_kernel<<<nsb, 256, 0, stream>>>(OFF, BS, CUR);
    inv_kernel<<<nsb, 256, 0, stream>>>(CNT, INV);
    fill_kernel<<<(NEDG + 255) / 256, 256, 0, stream>>>(el, pl, CUR, EDG);

    const int gblocks = (NN + 63) / 64;  // 782
    const int ewblocks = (NN + 3) / 4;
    for (int step = 0; step < 2; ++step) {
        const float* hsrc = (step == 0) ? node_states : h;
        // 6 chunk GEMMs from h
        gemm9<<<gblocks, 512, 0, stream>>>(hsrc, 1, BPp, 6, msg_b, CH0, CH45, 4);
        // edge aggregation -> MSGB (bf16)
        agg_kernel<<<ewblocks, 256, 0, stream>>>(CH0, CH45, OFF, EDG, GATE, INV, MSGB);
        // gh{r,z,n} = h @ Whh^T  -> CH0 slabs 0..2 (agg already consumed chunks)
        gemm9<<<gblocks, 512, 0, stream>>>(hsrc, 1, BPhh, 3, nullptr, CH0, nullptr, 4);
        // gi{r,z,n} = msg @ Wih^T -> CH0 slab 3, CH45 slabs 0..1
        gemm9<<<gblocks, 512, 0, stream>>>(MSGB, 0, BPih, 3, nullptr,
                                           CH0 + 3 * NH, CH45, 1);
        // streaming GRU elementwise, in-place h
        gru_ew<<<ewblocks, 256, 0, stream>>>(h, hsrc, CH0, CH0 + 3 * NH, CH45, gbih, gbhh);
    }
    hipMemcpyAsync(out2, node_states, NH * sizeof(float), hipMemcpyDeviceToDevice, stream);
}